// Round 1
// baseline (150.718 us; speedup 1.0000x reference)
//
#include <hip/hip_runtime.h>
#include <math.h>

#define BB 32
#define LL 4096
#define DD 1024

// Kernel 1: dlT[l*BB + b] = dot(doc[b,l,:], W[l,:]) + bias[l]
// One 64-lane wave per (b,l) row. Lane-strided float4 loads: 1 KiB per
// wave-instruction, fully coalesced. Transposed store so kernel 2 sees
// wave-uniform dl addresses (scalar-load friendly).
__global__ __launch_bounds__(256) void k_dot(const float* __restrict__ doc,
                                             const float* __restrict__ W,
                                             const float* __restrict__ bias,
                                             float* __restrict__ dlT) {
  const int wid  = (blockIdx.x * 256 + threadIdx.x) >> 6;  // row id in [0, BB*LL)
  const int lane = threadIdx.x & 63;
  const int b = wid >> 12;          // wid / LL
  const int l = wid & (LL - 1);     // wid % LL

  const float4* dp = reinterpret_cast<const float4*>(doc + ((size_t)wid << 10));
  const float4* wp = reinterpret_cast<const float4*>(W + ((size_t)l << 10));

  float acc = 0.f;
#pragma unroll
  for (int it = 0; it < 4; ++it) {
    float4 a = dp[lane + it * 64];
    float4 w = wp[lane + it * 64];
    acc += a.x * w.x + a.y * w.y + a.z * w.z + a.w * w.w;
  }
#pragma unroll
  for (int off = 32; off > 0; off >>= 1) acc += __shfl_down(acc, off);

  if (lane == 0) dlT[l * BB + b] = acc + bias[l];
}

// Kernel 2: part[s][b*LL + j] = sum_{l in chunk s} dlT[l*BB+b] * G[l*LL+j]
// Thread = one output column j; 32 per-batch accumulators in VGPRs.
// dlT reads are wave-uniform (no threadIdx in the address) -> compiler emits
// s_load; G reads are coalesced across the wave.
__global__ __launch_bounds__(256) void k_gemm(const float* __restrict__ dlT,
                                              const float* __restrict__ G,
                                              float* __restrict__ part,
                                              int chunk_l) {
  const int jt = blockIdx.x & 15;   // j-tile (16 tiles of 256 columns)
  const int s  = blockIdx.x >> 4;   // l-chunk
  const int j  = jt * 256 + threadIdx.x;
  const int l0 = s * chunk_l;

  float acc[BB];
#pragma unroll
  for (int b = 0; b < BB; ++b) acc[b] = 0.f;

#pragma unroll 4
  for (int il = 0; il < chunk_l; ++il) {
    const int l = l0 + il;
    const float g = G[(size_t)l * LL + j];
    const float4* dr4 = reinterpret_cast<const float4*>(dlT + (size_t)l * BB);
#pragma unroll
    for (int bq = 0; bq < BB / 4; ++bq) {
      float4 v = dr4[bq];            // wave-uniform -> scalar load
      acc[bq * 4 + 0] += v.x * g;
      acc[bq * 4 + 1] += v.y * g;
      acc[bq * 4 + 2] += v.z * g;
      acc[bq * 4 + 3] += v.w * g;
    }
  }

  float* po = part + (size_t)s * (BB * LL);
#pragma unroll
  for (int b = 0; b < BB; ++b) po[(size_t)b * LL + j] = acc[b];
}

// Kernel 3: out[i] = sigmoid(sum_s part[s][i])
__global__ __launch_bounds__(256) void k_reduce(const float* __restrict__ part,
                                                float* __restrict__ out,
                                                int nchunks) {
  const int i = blockIdx.x * 256 + threadIdx.x;  // i in [0, BB*LL)
  float s = 0.f;
  for (int c = 0; c < nchunks; ++c) s += part[(size_t)c * (BB * LL) + i];
  out[i] = 1.f / (1.f + expf(-s));
}

extern "C" void kernel_launch(void* const* d_in, const int* in_sizes, int n_in,
                              void* d_out, int out_size, void* d_ws, size_t ws_size,
                              hipStream_t stream) {
  const float* doc  = (const float*)d_in[0];  // [B, L, D]
  const float* W    = (const float*)d_in[1];  // [L, D]
  const float* bias = (const float*)d_in[2];  // [L]
  const float* G    = (const float*)d_in[3];  // [L, L]
  float* out = (float*)d_out;                 // [B, L]

  float* dlT = (float*)d_ws;                              // BB*LL floats = 512 KB
  const size_t dl_bytes  = (size_t)BB * LL * sizeof(float);
  const size_t per_chunk = (size_t)BB * LL * sizeof(float);
  float* part = (float*)((char*)d_ws + dl_bytes);

  // l-split factor: 32 chunks (512 blocks for k_gemm) if workspace allows.
  int nchunks = 32;
  size_t avail = ws_size > dl_bytes ? (ws_size - dl_bytes) / per_chunk : 0;
  if ((size_t)nchunks > avail) {
    nchunks = 1;
    while ((size_t)(nchunks * 2) <= avail && nchunks * 2 <= 32) nchunks *= 2;
  }
  const int chunk_l = LL / nchunks;

  k_dot<<<dim3((BB * LL) / 4), dim3(256), 0, stream>>>(doc, W, bias, dlT);
  k_gemm<<<dim3(16 * nchunks), dim3(256), 0, stream>>>(dlT, G, part, chunk_l);
  k_reduce<<<dim3((BB * LL) / 256), dim3(256), 0, stream>>>(part, out, nchunks);
}

// Round 2
// 148.826 us; speedup vs baseline: 1.0127x; 1.0127x over previous
//
#include <hip/hip_runtime.h>
#include <math.h>

#define BB 32
#define LL 4096
#define DD 1024
#define CH 64   // l-subtile staged in LDS by k_gemm

// Kernel 1: dlT[l*BB + b] = dot(doc[b,l,:], W[l,:]) + bias[l]
// One 64-lane wave per (b,l) row. Wave id decodes as l = wid>>5, b = wid&31,
// so the 4 waves of a block share the same l -> W row is fetched once and
// hits L1 for the other 3 waves (cuts L3 W traffic 4x).
__global__ __launch_bounds__(256) void k_dot(const float* __restrict__ doc,
                                             const float* __restrict__ W,
                                             const float* __restrict__ bias,
                                             float* __restrict__ dlT) {
  const int wid  = (blockIdx.x * 256 + threadIdx.x) >> 6;  // [0, BB*LL)
  const int lane = threadIdx.x & 63;
  const int l = wid >> 5;
  const int b = wid & 31;

  const float4* dp = reinterpret_cast<const float4*>(doc) + ((size_t)(b * LL + l) << 8);
  const float4* wp = reinterpret_cast<const float4*>(W) + ((size_t)l << 8);

  float acc = 0.f;
#pragma unroll
  for (int it = 0; it < 4; ++it) {
    float4 a = dp[lane + it * 64];
    float4 w = wp[lane + it * 64];
    acc = fmaf(a.x, w.x, acc);
    acc = fmaf(a.y, w.y, acc);
    acc = fmaf(a.z, w.z, acc);
    acc = fmaf(a.w, w.w, acc);
  }
#pragma unroll
  for (int off = 32; off > 0; off >>= 1) acc += __shfl_down(acc, off);

  if (lane == 0) dlT[(l << 5) + b] = acc + bias[l];
}

// Kernel 2: part[s][b*LL + j] = sum_{l in chunk s} dlT[l*BB+b] * G[l*LL+j]
// Thread = one output column j. The dlT chunk is staged in LDS; inner-loop
// dlT reads are wave-uniform LDS broadcasts (no VMEM latency on the critical
// path). 16 j-tiles x nchunks blocks.
__global__ __launch_bounds__(256) void k_gemm(const float* __restrict__ dlT,
                                              const float* __restrict__ G,
                                              float* __restrict__ part,
                                              int chunk_l) {
  __shared__ float sdl[CH * BB];
  const int jt = blockIdx.x & 15;   // j-tile (16 tiles of 256 columns)
  const int s  = blockIdx.x >> 4;   // l-chunk
  const int j  = (jt << 8) + threadIdx.x;
  const int l0 = s * chunk_l;

  float acc[BB];
#pragma unroll
  for (int b = 0; b < BB; ++b) acc[b] = 0.f;

  for (int t0 = 0; t0 < chunk_l; t0 += CH) {
    // cooperative load of CH*BB = 2048 floats (8 KB), coalesced float4
    {
      const float4* src = reinterpret_cast<const float4*>(dlT + (size_t)(l0 + t0) * BB);
      float4* dst = reinterpret_cast<float4*>(sdl);
#pragma unroll
      for (int k = 0; k < (CH * BB / 4) / 256; ++k)
        dst[k * 256 + threadIdx.x] = src[k * 256 + threadIdx.x];
    }
    __syncthreads();

#pragma unroll 2
    for (int il = 0; il < CH; ++il) {
      const float g = G[(size_t)(l0 + t0 + il) * LL + j];
      const float4* dr = reinterpret_cast<const float4*>(sdl + il * BB);
#pragma unroll
      for (int bq = 0; bq < BB / 4; ++bq) {
        float4 v = dr[bq];          // uniform address -> LDS broadcast
        acc[bq * 4 + 0] = fmaf(v.x, g, acc[bq * 4 + 0]);
        acc[bq * 4 + 1] = fmaf(v.y, g, acc[bq * 4 + 1]);
        acc[bq * 4 + 2] = fmaf(v.z, g, acc[bq * 4 + 2]);
        acc[bq * 4 + 3] = fmaf(v.w, g, acc[bq * 4 + 3]);
      }
    }
    __syncthreads();
  }

  float* po = part + (size_t)s * (BB * LL);
#pragma unroll
  for (int b = 0; b < BB; ++b) po[(size_t)b * LL + j] = acc[b];
}

// Kernel 3: out[i] = sigmoid(sum_s part[s][i])
__global__ __launch_bounds__(256) void k_reduce(const float* __restrict__ part,
                                                float* __restrict__ out,
                                                int nchunks) {
  const int i = blockIdx.x * 256 + threadIdx.x;  // [0, BB*LL)
  float s = 0.f;
#pragma unroll 8
  for (int c = 0; c < nchunks; ++c) s += part[(size_t)c * (BB * LL) + i];
  out[i] = 1.f / (1.f + expf(-s));
}

extern "C" void kernel_launch(void* const* d_in, const int* in_sizes, int n_in,
                              void* d_out, int out_size, void* d_ws, size_t ws_size,
                              hipStream_t stream) {
  const float* doc  = (const float*)d_in[0];  // [B, L, D]
  const float* W    = (const float*)d_in[1];  // [L, D]
  const float* bias = (const float*)d_in[2];  // [L]
  const float* G    = (const float*)d_in[3];  // [L, L]
  float* out = (float*)d_out;                 // [B, L]

  float* dlT = (float*)d_ws;                              // BB*LL floats = 512 KB
  const size_t dl_bytes  = (size_t)BB * LL * sizeof(float);
  const size_t per_chunk = (size_t)BB * LL * sizeof(float);
  float* part = (float*)((char*)d_ws + dl_bytes);

  // l-split: 64 chunks (1024 blocks, 4 waves/SIMD) if workspace allows.
  int nchunks = 64;
  size_t avail = ws_size > dl_bytes ? (ws_size - dl_bytes) / per_chunk : 0;
  if ((size_t)nchunks > avail) {
    nchunks = 1;
    while ((size_t)(nchunks * 2) <= avail && nchunks * 2 <= 64) nchunks *= 2;
  }
  const int chunk_l = LL / nchunks;   // multiple of CH for nchunks <= 64

  k_dot<<<dim3((BB * LL) / 4), dim3(256), 0, stream>>>(doc, W, bias, dlT);
  k_gemm<<<dim3(16 * nchunks), dim3(256), 0, stream>>>(dlT, G, part, chunk_l);
  k_reduce<<<dim3((BB * LL) / 256), dim3(256), 0, stream>>>(part, out, nchunks);
}